// Round 6
// baseline (330.380 us; speedup 1.0000x reference)
//
#include <hip/hip_runtime.h>

// MPS VQE, SINGLE-dispatch design.
// H symmetric (bitwise 0.5*(A+A^T)) =>
//   (1) <psi|H^2|psi> = ||H psi||^2  -> only ONE matvec needed
//   (2) SYMV tiling: read only upper-triangular 64x64 tiles (2080/4096)
//       -> ~34.1 MB of H reads (half L3-resident).
// Structure (no grid.sync — R3 showed ~60us/sync; no per-block psi rebuild —
// R4 showed that regression):
//   blocks 0..63   = diagonal tiles, dispatched FIRST: build psi slice from
//                    the MPS cores, publish psi, zero hpsi slice, set flag[bi]
//                    (release), then compute their own tile.
//   blocks 64..2079 = off-diag tiles: spin (acquire) on flags[0],[bi],[bj],
//                    load psi slices, compute tile, atomic-scatter both slices.
//   Last-finishing block (atomic counter, R4/R5-verified pattern) computes the
//   three double-precision dots + finalizes.
// Poison-safety: flags tested against ==1 (poison 0xAAAAAAAA != 1); cnt is
// reset by block 0 before flags[0] is released, and every block waits on
// flags[0] before touching cnt.

#define DIM 4096
#define BOND 8
#define NMID 10
#define T 64
#define NT (DIM / T)                     // 64
#define NOFF (NT * (NT - 1) / 2)         // 2016
#define NBLK (NT + NOFF)                 // 2080

// ws layout: psi[4096] f32 | hpsi[4096] f32 | cnt int | flags[64] int

__global__ __launch_bounds__(256, 6) void fused_vqe(
    const float* __restrict__ core0,      // (2, 8)
    const float* __restrict__ cores_mid,  // (10, 8, 2, 8)
    const float* __restrict__ core_last,  // (8, 2)
    const float* __restrict__ H,          // (4096, 4096) symmetric
    float* __restrict__ psi_g,
    float* __restrict__ hpsi_g,
    int* __restrict__ cnt,
    int* __restrict__ flags,
    float* __restrict__ out) {
  __shared__ float c0[16], cm[NMID * 128], cl[16];
  __shared__ float xI[T], xJ[T];
  __shared__ float rowp[T * 17];   // [row][g], stride 17 (conflict-benign)
  __shared__ float colp[16 * 68];  // [rowgroup][col], stride 68 (float4-aligned)
  __shared__ double sred[12];
  __shared__ int s_old;

  const bool diag = (blockIdx.x < NT);
  int bi, bj;
  if (diag) {
    bi = bj = blockIdx.x;
  } else {
    int rem = blockIdx.x - NT;  // off-diag linear index over (bi<bj)
    bi = 0;
    while (rem >= NT - 1 - bi) { rem -= (NT - 1 - bi); ++bi; }
    bj = bi + 1 + rem;
  }

  if (diag) {
    // ---- producer: build psi slice, zero hpsi slice, release flag ----
    if (threadIdx.x < 16) {
      c0[threadIdx.x] = core0[threadIdx.x];
      cl[threadIdx.x] = core_last[threadIdx.x];
    }
    for (int j = threadIdx.x; j < NMID * 128; j += 256) cm[j] = cores_mid[j];
    __syncthreads();

    if (threadIdx.x < T) {
      const int idx = bi * T + threadIdx.x;
      float v[BOND], nv[BOND];
      const int s0 = (idx >> 11) & 1;
#pragma unroll
      for (int a = 0; a < BOND; a++) v[a] = c0[s0 * BOND + a];
#pragma unroll
      for (int i = 0; i < NMID; i++) {
        const int p = (idx >> (10 - i)) & 1;
        const float* M = &cm[i * 128 + p * BOND];  // M[a][b] at M[a*16+b]
#pragma unroll
        for (int b = 0; b < BOND; b++) nv[b] = v[0] * M[b];
#pragma unroll
        for (int a = 1; a < BOND; a++) {
#pragma unroll
          for (int b = 0; b < BOND; b++) nv[b] += v[a] * M[a * 16 + b];
        }
#pragma unroll
        for (int a = 0; a < BOND; a++) v[a] = nv[a];
      }
      const int pl = idx & 1;
      float ps = 0.f;
#pragma unroll
      for (int a = 0; a < BOND; a++) ps += v[a] * cl[a * 2 + pl];
      xI[threadIdx.x] = ps;
      xJ[threadIdx.x] = ps;
      psi_g[idx] = ps;
    } else if (threadIdx.x < 2 * T) {
      hpsi_g[bi * T + (threadIdx.x - T)] = 0.f;
    } else if (threadIdx.x == 2 * T && bi == 0) {
      __hip_atomic_store(cnt, 0, __ATOMIC_RELAXED, __HIP_MEMORY_SCOPE_AGENT);
    }
    __syncthreads();
    if (threadIdx.x == 0) {
      __threadfence();
      __hip_atomic_store(&flags[bi], 1, __ATOMIC_RELEASE,
                         __HIP_MEMORY_SCOPE_AGENT);
    }
    __syncthreads();
  } else {
    // ---- consumer: wait for producers, then load psi slices ----
    if (threadIdx.x == 0) {
      while (__hip_atomic_load(&flags[0], __ATOMIC_ACQUIRE,
                               __HIP_MEMORY_SCOPE_AGENT) != 1)
        __builtin_amdgcn_s_sleep(1);
      while (__hip_atomic_load(&flags[bi], __ATOMIC_ACQUIRE,
                               __HIP_MEMORY_SCOPE_AGENT) != 1)
        __builtin_amdgcn_s_sleep(1);
      while (__hip_atomic_load(&flags[bj], __ATOMIC_ACQUIRE,
                               __HIP_MEMORY_SCOPE_AGENT) != 1)
        __builtin_amdgcn_s_sleep(1);
    }
    __syncthreads();
    if (threadIdx.x < T) {
      xI[threadIdx.x] = __hip_atomic_load(&psi_g[bi * T + threadIdx.x],
                                          __ATOMIC_RELAXED,
                                          __HIP_MEMORY_SCOPE_AGENT);
    } else if (threadIdx.x < 2 * T) {
      xJ[threadIdx.x - T] = __hip_atomic_load(&psi_g[bj * T + threadIdx.x - T],
                                              __ATOMIC_RELAXED,
                                              __HIP_MEMORY_SCOPE_AGENT);
    }
    __syncthreads();
  }

  // ---- tile symv: 64x64, 16 elems/thread, no cross-lane ops in loop ----
  const int g = threadIdx.x & 15;   // column group
  const int rg = threadIdx.x >> 4;  // row group (0..15)
  const int c = g * 4;
  const float4 pj = *reinterpret_cast<const float4*>(&xJ[c]);
  const float* __restrict__ base = H + (size_t)(bi * T) * DIM + bj * T;

  float4 aJ = {0.f, 0.f, 0.f, 0.f};
#pragma unroll
  for (int p = 0; p < 4; ++p) {
    const int r = p * 16 + rg;
    const float4 a =
        *reinterpret_cast<const float4*>(base + (size_t)r * DIM + c);
    const float xr = xI[r];
    aJ.x += a.x * xr; aJ.y += a.y * xr; aJ.z += a.z * xr; aJ.w += a.w * xr;
    rowp[r * 17 + g] = a.x * pj.x + a.y * pj.y + a.z * pj.z + a.w * pj.w;
  }
  *reinterpret_cast<float4*>(&colp[rg * 68 + c]) = aJ;
  __syncthreads();

  // deferred reductions: threads 0..63 rows, 64..127 cols (concurrent)
  if (threadIdx.x < T) {
    float s = 0.f;
#pragma unroll
    for (int q = 0; q < 16; ++q) s += rowp[threadIdx.x * 17 + q];
    atomicAdd(&hpsi_g[bi * T + threadIdx.x], s);
  } else if (threadIdx.x < 2 * T && !diag) {
    const int t = threadIdx.x - T;
    float s = 0.f;
#pragma unroll
    for (int q = 0; q < 16; ++q) s += colp[q * 68 + t];
    atomicAdd(&hpsi_g[bj * T + t], s);
  }
  __syncthreads();

  // ---- last-finishing block: three double dots + finalize ----
  if (threadIdx.x == 0) {
    // ensure cnt has been reset (flags[0] released after the reset)
    while (__hip_atomic_load(&flags[0], __ATOMIC_ACQUIRE,
                             __HIP_MEMORY_SCOPE_AGENT) != 1)
      __builtin_amdgcn_s_sleep(1);
    __threadfence();
    s_old = atomicAdd(cnt, 1);
  }
  __syncthreads();
  if (s_old == NBLK - 1) {
    __threadfence();
    const int wave = threadIdx.x >> 6;
    const int lane = threadIdx.x & 63;
    double n = 0.0, ph = 0.0, hh = 0.0;
    for (int i = threadIdx.x; i < DIM; i += 256) {
      const float p = __hip_atomic_load(&psi_g[i], __ATOMIC_RELAXED,
                                        __HIP_MEMORY_SCOPE_AGENT);
      const float h = __hip_atomic_load(&hpsi_g[i], __ATOMIC_RELAXED,
                                        __HIP_MEMORY_SCOPE_AGENT);
      const double pd = (double)p, hd = (double)h;
      n += pd * pd;
      ph += pd * hd;
      hh += hd * hd;
    }
#pragma unroll
    for (int off = 32; off > 0; off >>= 1) {
      n += __shfl_down(n, off, 64);
      ph += __shfl_down(ph, off, 64);
      hh += __shfl_down(hh, off, 64);
    }
    if (lane == 0) { sred[wave] = n; sred[4 + wave] = ph; sred[8 + wave] = hh; }
    __syncthreads();
    if (threadIdx.x == 0) {
      double N = 0.0, P = 0.0, HH = 0.0;
#pragma unroll
      for (int w = 0; w < 4; w++) { N += sred[w]; P += sred[4 + w]; HH += sred[8 + w]; }
      const double e = P / N;
      const double e2 = HH / N;
      double var = e2 - e * e;
      if (var < 0.0) var = 0.0;
      out[0] = (float)e;
      out[1] = (float)var;
    }
  }
}

extern "C" void kernel_launch(void* const* d_in, const int* in_sizes, int n_in,
                              void* d_out, int out_size, void* d_ws, size_t ws_size,
                              hipStream_t stream) {
  const float* core0 = (const float*)d_in[0];
  const float* cores_mid = (const float*)d_in[1];
  const float* core_last = (const float*)d_in[2];
  const float* H = (const float*)d_in[3];

  float* psi = (float*)d_ws;
  float* hpsi = psi + DIM;
  int* cnt = (int*)(hpsi + DIM);
  int* flags = cnt + 1;

  fused_vqe<<<NBLK, 256, 0, stream>>>(core0, cores_mid, core_last, H,
                                      psi, hpsi, cnt, flags, (float*)d_out);
}

// Round 7
// 135.763 us; speedup vs baseline: 2.4335x; 2.4335x over previous
//
#include <hip/hip_runtime.h>

// MPS VQE, 2-dispatch design (best-verified structure, R5).
// H symmetric (bitwise 0.5*(A+A^T)) =>
//   (1) <psi|H^2|psi> = ||H psi||^2  -> only ONE matvec needed
//   (2) SYMV tiling: read only upper-triangular 128x128 tiles (528/1024).
// Lessons: no grid.sync (R3: ~60us/sync); no per-block psi rebuild (R4);
// no agent-scope spin producer/consumer (R6: 265us trickle).
// R7: split each tile into 2x 64-row half-blocks -> 1056 blocks (~4/CU,
// 16 waves/CU) for 2x memory-level parallelism vs R5's 528.

#define DIM 4096
#define BOND 8
#define NMID 10
#define T 128
#define TR 64                          // rows per block (tile half)
#define NT (DIM / T)                   // 32
#define NTILE (NT * (NT + 1) / 2)      // 528
#define NBLK (2 * NTILE)               // 1056

// ws layout: psi[4096] f32 | hpsi[4096] f32 | cnt int

// ---------------- Kernel 1: build psi + zero hpsi + zero cnt ----------------
__global__ __launch_bounds__(256) void init_kernel(
    const float* __restrict__ core0,      // (2, 8)
    const float* __restrict__ cores_mid,  // (10, 8, 2, 8)
    const float* __restrict__ core_last,  // (8, 2)
    float* __restrict__ psi_g,
    float* __restrict__ hpsi_g,
    int* __restrict__ cnt) {
  __shared__ float c0[16], cm[NMID * 128], cl[16];

  if (threadIdx.x < 16) {
    c0[threadIdx.x] = core0[threadIdx.x];
    cl[threadIdx.x] = core_last[threadIdx.x];
  }
  for (int j = threadIdx.x; j < NMID * 128; j += 256) cm[j] = cores_mid[j];
  __syncthreads();

  const int idx = blockIdx.x * 256 + threadIdx.x;  // 0..4095
  hpsi_g[idx] = 0.f;
  if (idx == 0) *cnt = 0;

  float v[BOND], nv[BOND];
  const int s0 = (idx >> 11) & 1;
#pragma unroll
  for (int a = 0; a < BOND; a++) v[a] = c0[s0 * BOND + a];
#pragma unroll
  for (int i = 0; i < NMID; i++) {
    const int p = (idx >> (10 - i)) & 1;
    const float* M = &cm[i * 128 + p * BOND];  // M[a][b] at M[a*16 + b]
#pragma unroll
    for (int b = 0; b < BOND; b++) nv[b] = v[0] * M[b];
#pragma unroll
    for (int a = 1; a < BOND; a++) {
#pragma unroll
      for (int b = 0; b < BOND; b++) nv[b] += v[a] * M[a * 16 + b];
    }
#pragma unroll
    for (int a = 0; a < BOND; a++) v[a] = nv[a];
  }
  const int pl = idx & 1;
  float ps = 0.f;
#pragma unroll
  for (int a = 0; a < BOND; a++) ps += v[a] * cl[a * 2 + pl];
  psi_g[idx] = ps;
}

// ---------------- Kernel 2: symv half-tiles + last-block dots ----------------
__global__ __launch_bounds__(256) void symv_kernel(
    const float* __restrict__ H,
    const float* __restrict__ psi_g,
    float* __restrict__ hpsi_g,
    int* __restrict__ cnt,
    float* __restrict__ out) {
  __shared__ float xI[T], xJ[T];          // full tile slices of psi
  __shared__ float rowp[TR * 33];         // [row][colgroup], stride 33
  __shared__ float colp[8 * 132];         // [rowgroup][col], stride 132
  __shared__ double sred[12];
  __shared__ int s_old;

  const int tile = blockIdx.x >> 1;
  const int hlf = blockIdx.x & 1;  // which 64-row half of the tile
  int rem = tile;
  int bi = 0;
  while (rem >= NT - bi) { rem -= (NT - bi); ++bi; }
  const int bj = bi + rem;
  const bool diag = (bi == bj);

  if (threadIdx.x < T) xI[threadIdx.x] = psi_g[bi * T + threadIdx.x];
  else xJ[threadIdx.x - T] = psi_g[bj * T + threadIdx.x - T];
  __syncthreads();

  const int g = threadIdx.x & 31;   // column group (float4) 0..31
  const int rg = threadIdx.x >> 5;  // row group 0..7
  const int c = g * 4;

  const float4 pj = *reinterpret_cast<const float4*>(&xJ[c]);  // loop-invariant
  const float* __restrict__ base =
      H + (size_t)(bi * T + hlf * TR) * DIM + bj * T;

  // K-loop: 8 independent float4 loads/thread; NO cross-lane ops inside.
  float4 aJ = {0.f, 0.f, 0.f, 0.f};
#pragma unroll
  for (int p = 0; p < 8; ++p) {
    const int r = p * 8 + rg;  // local row 0..63
    const float4 a =
        *reinterpret_cast<const float4*>(base + (size_t)r * DIM + c);
    const float xr = xI[hlf * TR + r];
    aJ.x += a.x * xr; aJ.y += a.y * xr; aJ.z += a.z * xr; aJ.w += a.w * xr;
    rowp[r * 33 + g] = a.x * pj.x + a.y * pj.y + a.z * pj.z + a.w * pj.w;
  }
  *reinterpret_cast<float4*>(&colp[rg * 132 + c]) = aJ;
  __syncthreads();

  // deferred reduce: rows (threads 0..127, 2 per row) and cols (128..255)
  if (threadIdx.x < 2 * TR) {
    const int r = threadIdx.x >> 1;
    const int h2 = threadIdx.x & 1;
    float s = 0.f;
#pragma unroll
    for (int i = 0; i < 16; ++i) s += rowp[r * 33 + h2 * 16 + i];
    s += __shfl_down(s, 1, 64);
    if (h2 == 0) atomicAdd(&hpsi_g[bi * T + hlf * TR + r], s);
  } else if (!diag) {
    const int col = threadIdx.x - 128;  // 0..127
    float s = 0.f;
#pragma unroll
    for (int q = 0; q < 8; ++q) s += colp[q * 132 + col];
    atomicAdd(&hpsi_g[bj * T + col], s);
  }
  __syncthreads();

  // ---- last-finishing block: three double dots + finalize (R4/R5-verified) --
  if (threadIdx.x == 0) {
    __threadfence();
    s_old = atomicAdd(cnt, 1);
  }
  __syncthreads();
  if (s_old == NBLK - 1) {
    __threadfence();
    const int wave = threadIdx.x >> 6;
    const int lane = threadIdx.x & 63;
    double n = 0.0, ph = 0.0, hh = 0.0;
    for (int i = threadIdx.x; i < DIM; i += 256) {
      const float p = __hip_atomic_load(&psi_g[i], __ATOMIC_RELAXED,
                                        __HIP_MEMORY_SCOPE_AGENT);
      const float h = __hip_atomic_load(&hpsi_g[i], __ATOMIC_RELAXED,
                                        __HIP_MEMORY_SCOPE_AGENT);
      const double pd = (double)p, hd = (double)h;
      n += pd * pd;
      ph += pd * hd;
      hh += hd * hd;
    }
#pragma unroll
    for (int off = 32; off > 0; off >>= 1) {
      n += __shfl_down(n, off, 64);
      ph += __shfl_down(ph, off, 64);
      hh += __shfl_down(hh, off, 64);
    }
    if (lane == 0) { sred[wave] = n; sred[4 + wave] = ph; sred[8 + wave] = hh; }
    __syncthreads();
    if (threadIdx.x == 0) {
      double N = 0.0, P = 0.0, HH = 0.0;
#pragma unroll
      for (int w = 0; w < 4; w++) { N += sred[w]; P += sred[4 + w]; HH += sred[8 + w]; }
      const double e = P / N;
      const double e2 = HH / N;
      double var = e2 - e * e;
      if (var < 0.0) var = 0.0;
      out[0] = (float)e;
      out[1] = (float)var;
    }
  }
}

extern "C" void kernel_launch(void* const* d_in, const int* in_sizes, int n_in,
                              void* d_out, int out_size, void* d_ws, size_t ws_size,
                              hipStream_t stream) {
  const float* core0 = (const float*)d_in[0];
  const float* cores_mid = (const float*)d_in[1];
  const float* core_last = (const float*)d_in[2];
  const float* H = (const float*)d_in[3];

  float* psi = (float*)d_ws;
  float* hpsi = psi + DIM;
  int* cnt = (int*)(hpsi + DIM);

  init_kernel<<<DIM / 256, 256, 0, stream>>>(core0, cores_mid, core_last,
                                             psi, hpsi, cnt);
  symv_kernel<<<NBLK, 256, 0, stream>>>(H, psi, hpsi, cnt, (float*)d_out);
}